// Round 9
// baseline (202.910 us; speedup 1.0000x reference)
//
#include <hip/hip_runtime.h>
#include <hip/hip_bf16.h>

typedef __bf16 bf16x8 __attribute__((ext_vector_type(8)));
typedef float floatx4 __attribute__((ext_vector_type(4)));

__device__ __forceinline__ unsigned short f2bf(float f) {
  __bf16 b = (__bf16)f;
  return __builtin_bit_cast(unsigned short, b);
}

// ---------------------------------------------------------------------------
// Kernel 1: decode w1 bits -> bf16 {-1,0,+1} in MFMA-FRAGMENT-TRANSPOSED order:
//   w1t[(kq*256 + row)*8 + k]  holds W[row][kq*8 + k],  kq in [0,104)
// (zero-padded above col 783). 16 consecutive rows = 256 contiguous bytes ->
// direct-to-VGPR B-fragment loads coalesce perfectly.
// ---------------------------------------------------------------------------
__global__ void decode_w1_kernel(const int* __restrict__ w1p,
                                 const int* __restrict__ m1p,
                                 unsigned short* __restrict__ w1t) {
  int t = blockIdx.x * 256 + threadIdx.x;   // [0, 104*256)
  int r = t & 255;                          // row 0..255
  int j = t >> 8;                           // byte group (kq) 0..103
  unsigned short vals[8];
#pragma unroll
  for (int k = 0; k < 8; ++k) vals[k] = 0;
  if (j < 98) {
    unsigned int v = (unsigned int)w1p[r * 98 + j];
    unsigned int m = (unsigned int)m1p[r * 98 + j];
#pragma unroll
    for (int k = 0; k < 8; ++k) {           // MSB-first per byte (matches _unpack)
      unsigned int bit = (v >> (7 - k)) & 1u;
      unsigned int mk  = (m >> (7 - k)) & 1u;
      vals[k] = (unsigned short)(mk ? (bit ? 0x3F80u : 0xBF80u) : 0u);  // +1/-1/0
    }
  }
  uint4 pack;
  pack.x = (unsigned)vals[0] | ((unsigned)vals[1] << 16);
  pack.y = (unsigned)vals[2] | ((unsigned)vals[3] << 16);
  pack.z = (unsigned)vals[4] | ((unsigned)vals[5] << 16);
  pack.w = (unsigned)vals[6] | ((unsigned)vals[7] << 16);
  *reinterpret_cast<uint4*>(w1t + t * 8) = pack;
}

// ---------------------------------------------------------------------------
// Kernel 2: xform_x -- x[32768][784] fp32 -> xt[kq][32768][8] bf16 A-fragment
// layout, kq in [0,100) (kq 98,99 zero pad; kq>=100 never read).
// Pure streaming: no LDS, no barriers. Writes are perfectly coalesced (wave =
// 1KB contiguous run); reads are 32B/lane strided but x (103MB) is L3-resident
// after first touch, and every fetched byte is consumed across kq passes.
// This kernel DIRECTLY measures the achievable x-stream bandwidth.
// ---------------------------------------------------------------------------
__global__ __launch_bounds__(256, 4) void xform_x_kernel(
    const float* __restrict__ x,
    unsigned short* __restrict__ xt) {
  const int kq = blockIdx.x >> 7;           // 0..99   (slow: row-streaming)
  const int r  = ((blockIdx.x & 127) << 8) + threadIdx.x;  // 0..32767
  uint4 pack;
  if (kq < 98) {
    const float* p = x + (size_t)r * 784 + kq * 8;
    float4 a = *reinterpret_cast<const float4*>(p);
    float4 b = *reinterpret_cast<const float4*>(p + 4);
    pack.x = (unsigned)f2bf(a.x) | ((unsigned)f2bf(a.y) << 16);
    pack.y = (unsigned)f2bf(a.z) | ((unsigned)f2bf(a.w) << 16);
    pack.z = (unsigned)f2bf(b.x) | ((unsigned)f2bf(b.y) << 16);
    pack.w = (unsigned)f2bf(b.z) | ((unsigned)f2bf(b.w) << 16);
  } else {
    pack = (uint4){0u, 0u, 0u, 0u};         // K pad 784..799
  }
  *reinterpret_cast<uint4*>(xt + ((size_t)kq * 32768 + r) * 8) = pack;
}

// ---------------------------------------------------------------------------
// Kernel 3: fused  h = relu(a1 * x@W1^T);  out = a2 * (h@W2^T)
// v9: PURE-DATAFLOW K-loop. Both operands fragment-major bf16 in global:
// per chunk per wave = 4 A-loads + 2 B-loads (256B-contiguous per quad) +
// 8 MFMA, ping-pong prefetched, fully unrolled. NO LDS / cvt / barriers in
// the K-loop; one barrier total (layer-2 exchange). BM=64, 512 thr, grid 512
// (2 blocks/CU, 16 waves/CU at ~100 VGPR < 128 cap -> no spills).
//   A-frag: A[m=l15][k=quad*8+j]; B-frag: B^T[n=l15][k=quad*8+j];
//   C/D: col=l15, row=quad*4+reg  (m89-verified layouts).
// ---------------------------------------------------------------------------
#define BM 64
#define NCH 25       // chunks of 32 cols; 800 cols (kq 0..99); kq>=100 skipped
#define HS_LD 264    // 256 + 8 pad: layer-2 Hs reads conflict-free
#define W2_LD 264
#define OFF_W2 16896 // shorts: Hs[64][264] = 16896

__global__ __launch_bounds__(512, 4) void fused_kernel(
    const unsigned short* __restrict__ xt,
    const unsigned short* __restrict__ w1t,
    const int* __restrict__ w2p,
    const int* __restrict__ m2p,
    const float* __restrict__ a1p,
    const float* __restrict__ a2p,
    float* __restrict__ out) {
  __shared__ unsigned short smem[64 * HS_LD + 16 * W2_LD];  // 42240 B, phase-2 only

  const int tid  = threadIdx.x;
  const int wave = tid >> 6;
  const int lane = tid & 63;
  const int l15  = lane & 15;
  const int quad = lane >> 4;
  const int row0 = blockIdx.x * BM;

  floatx4 acc[4][2];
#pragma unroll
  for (int i = 0; i < 4; ++i)
#pragma unroll
    for (int j = 0; j < 2; ++j) acc[i][j] = (floatx4){0.f, 0.f, 0.f, 0.f};

  // Per-lane fragment base pointers (chunk kc adds kc*4 sections).
  const unsigned short* xl = xt + ((size_t)quad * 32768 + row0 + l15) * 8;
  const unsigned short* wl = w1t + ((size_t)quad * 256 + wave * 32 + l15) * 8;

  bf16x8 afb[2][4], bfb[2][2];
  auto pref = [&](int kc, int b) {
#pragma unroll
    for (int mi = 0; mi < 4; ++mi)
      afb[b][mi] = *reinterpret_cast<const bf16x8*>(
          xl + (size_t)kc * 1048576 + mi * 128);      // 4*32768*8 shorts/chunk
#pragma unroll
    for (int nj = 0; nj < 2; ++nj)
      bfb[b][nj] = *reinterpret_cast<const bf16x8*>(
          wl + (size_t)kc * 8192 + nj * 128);         // 4*256*8 shorts/chunk
  };
  auto mm = [&](int b) {
#pragma unroll
    for (int mi = 0; mi < 4; ++mi)
#pragma unroll
      for (int nj = 0; nj < 2; ++nj)
        acc[mi][nj] = __builtin_amdgcn_mfma_f32_16x16x32_bf16(
            afb[b][mi], bfb[b][nj], acc[mi][nj], 0, 0, 0);
  };

  pref(0, 0);
#pragma unroll
  for (int kc = 0; kc < NCH; ++kc) {
    if (kc + 1 < NCH) pref(kc + 1, (kc + 1) & 1);
    mm(kc & 1);
  }

  // ---- epilogue layer 1: h = relu(a1*acc) -> Hs bf16 ----
  const float a1 = a1p[0];
  const float a2 = a2p[0];
#pragma unroll
  for (int mi = 0; mi < 4; ++mi) {
#pragma unroll
    for (int nj = 0; nj < 2; ++nj) {
      int col   = wave * 32 + nj * 16 + l15;
      int rbase = mi * 16 + quad * 4;
#pragma unroll
      for (int rr = 0; rr < 4; ++rr) {
        float h = fmaxf(a1 * acc[mi][nj][rr], 0.f);
        smem[(rbase + rr) * HS_LD + col] = f2bf(h);
      }
    }
  }
  // ---- decode w2 -> W2s[16][264] (rows 10..15 zero) ----
  if (tid < 320) {
    int rr = tid >> 5, j = tid & 31;
    unsigned int v = (unsigned int)w2p[rr * 32 + j];
    unsigned int m = (unsigned int)m2p[rr * 32 + j];
#pragma unroll
    for (int k = 0; k < 8; ++k) {
      unsigned int bit = (v >> (7 - k)) & 1u;
      unsigned int mk  = (m >> (7 - k)) & 1u;
      smem[OFF_W2 + rr * W2_LD + j * 8 + k] =
          (unsigned short)(mk ? (bit ? 0x3F80u : 0xBF80u) : 0u);
    }
  }
  for (int idx = tid; idx < 6 * 256; idx += 512) {
    int rr = 10 + (idx >> 8), c = idx & 255;
    smem[OFF_W2 + rr * W2_LD + c] = 0;
  }
  __syncthreads();   // the ONLY barrier in the kernel

  // ---- layer 2: out[64][10] = Hs @ W2s^T; waves 0..3, 16 rows each, K=256 ----
  if (wave < 4) {
    floatx4 o2 = (floatx4){0.f, 0.f, 0.f, 0.f};
#pragma unroll
    for (int ks = 0; ks < 8; ++ks) {
      bf16x8 ha = *reinterpret_cast<const bf16x8*>(
          &smem[(wave * 16 + l15) * HS_LD + ks * 32 + quad * 8]);
      bf16x8 wb = *reinterpret_cast<const bf16x8*>(
          &smem[OFF_W2 + l15 * W2_LD + ks * 32 + quad * 8]);
      o2 = __builtin_amdgcn_mfma_f32_16x16x32_bf16(ha, wb, o2, 0, 0, 0);
    }
    if (l15 < 10) {
#pragma unroll
      for (int rr = 0; rr < 4; ++rr) {
        int gr = row0 + wave * 16 + quad * 4 + rr;
        out[(size_t)gr * 10 + l15] = a2 * o2[rr];
      }
    }
  }
}

extern "C" void kernel_launch(void* const* d_in, const int* in_sizes, int n_in,
                              void* d_out, int out_size, void* d_ws, size_t ws_size,
                              hipStream_t stream) {
  const float* x   = (const float*)d_in[0];
  const int*   w1p = (const int*)d_in[1];
  const int*   m1p = (const int*)d_in[2];
  const float* a1  = (const float*)d_in[3];
  const int*   w2p = (const int*)d_in[4];
  const int*   m2p = (const int*)d_in[5];
  const float* a2  = (const float*)d_in[6];
  unsigned short* w1t = (unsigned short*)d_ws;                    // 416 KB
  unsigned short* xt  = (unsigned short*)((char*)d_ws + 425984);  // 100*32768*16B = 52.4 MB
  float* out = (float*)d_out;

  decode_w1_kernel<<<104, 256, 0, stream>>>(w1p, m1p, w1t);
  xform_x_kernel<<<100 * 128, 256, 0, stream>>>(x, xt);
  fused_kernel<<<512, 512, 0, stream>>>(xt, w1t, w2p, m2p, a1, a2, out);
}